// Round 8
// baseline (547.472 us; speedup 1.0000x reference)
//
#include <hip/hip_runtime.h>

#define N_NODES 50000
#define N_EDGES 400000
#define EP (N_EDGES + N_NODES)   // 450000 edges incl. self-loops
#define D 64
#define H 8
#define NEG_SLOPE 0.2f
#define LN_EPS 1e-5f
#define CHUNK 196
#define SCAN_BLOCKS 256
#define PAD_N 50048

typedef unsigned short ushort_t;
typedef unsigned int uint_t;
typedef __attribute__((ext_vector_type(8))) short short8;
typedef __attribute__((ext_vector_type(4))) float f32x4;
typedef __attribute__((ext_vector_type(2))) float f32x2;

#if defined(__has_builtin)
#if __has_builtin(__builtin_amdgcn_cvt_pk_bf16_f32)
#define HAVE_CVT_PK_BF16 1
#endif
#endif

__device__ __forceinline__ ushort_t f2bf(float f) {
    uint_t u = __float_as_uint(f);
    u += 0x7fffu + ((u >> 16) & 1u);          // round-to-nearest-even
    return (ushort_t)(u >> 16);
}
// pack two f32 -> packed bf16 pair (lo = a, hi = b)
__device__ __forceinline__ uint_t pack_bf2(float a, float b) {
#ifdef HAVE_CVT_PK_BF16
    typedef __attribute__((ext_vector_type(2))) __bf16 bf16x2_t;
    bf16x2_t v = __builtin_amdgcn_cvt_pk_bf16_f32(a, b);
    uint_t r;
    __builtin_memcpy(&r, &v, 4);
    return r;
#else
    return (uint_t)f2bf(a) | ((uint_t)f2bf(b) << 16);
#endif
}
// unpack a packed pair of bf16 (one u32) -> f32x2 {lo, hi}
__device__ __forceinline__ f32x2 mkf2(uint_t u) {
    f32x2 r;
    r.x = __uint_as_float(u << 16);
    r.y = __uint_as_float(u & 0xffff0000u);
    return r;
}
__device__ __forceinline__ f32x2 absf2(f32x2 a) {
    f32x2 r;
    r.x = __uint_as_float(__float_as_uint(a.x) & 0x7fffffffu);
    r.y = __uint_as_float(__float_as_uint(a.y) & 0x7fffffffu);
    return r;
}

// decode edge id -> (src, dst); ids >= N_EDGES are self-loops
__device__ __forceinline__ void edge_sd(const int* __restrict__ ei, int eid, int& s, int& d) {
    if (eid < N_EDGES) { s = ei[eid]; d = ei[N_EDGES + eid]; }
    else               { s = d = eid - N_EDGES; }
}

// ---------------- setup: edge histogram + bf16 conversions (one kernel) ----------------

__global__ __launch_bounds__(256) void setup_all(const int* __restrict__ ei, int* __restrict__ counts,
                                                 const float* __restrict__ x,
                                                 const float* __restrict__ Wl, const float* __restrict__ Wr,
                                                 ushort_t* __restrict__ xb, ushort_t* __restrict__ Wt) {
    int t = blockIdx.x * 256 + threadIdx.x;
    if (t < EP) {
        int s, d; edge_sd(ei, t, s, d);
        atomicAdd(&counts[d], 1);
        return;
    }
    t -= EP;
    if (t < N_NODES * 64) { xb[t] = f2bf(x[t]); return; }
    t -= N_NODES * 64;
    if (t >= 3 * 1024 * 64) return;
    int l = t >> 16, rem = t & 65535, col = rem >> 6, k = rem & 63;
    float v = (col < 512) ? Wl[((size_t)l * 64 + k) * 512 + col]
                          : Wr[((size_t)l * 64 + k) * 512 + (col - 512)];
    Wt[t] = f2bf(v);
}

// ---------------- CSR scans ----------------

__global__ __launch_bounds__(256) void csr_scan1(const int* __restrict__ counts, int* __restrict__ bsum) {
    __shared__ int sd[256];
    int t = threadIdx.x, b = blockIdx.x;
    int idx = b * CHUNK + t;
    sd[t] = (t < CHUNK && idx < N_NODES) ? counts[idx] : 0;
    __syncthreads();
    for (int d = 128; d > 0; d >>= 1) {
        if (t < d) sd[t] += sd[t + d];
        __syncthreads();
    }
    if (t == 0) bsum[b] = sd[0];
}

__global__ __launch_bounds__(256) void csr_scan2(int* __restrict__ bsum) {
    __shared__ int sd[256];
    int t = threadIdx.x;
    sd[t] = bsum[t];
    __syncthreads();
    for (int d = 1; d < 256; d <<= 1) {
        int v = (t >= d) ? sd[t - d] : 0;
        __syncthreads();
        if (t >= d) sd[t] += v;
        __syncthreads();
    }
    bsum[t] = (t > 0) ? sd[t - 1] : 0;   // exclusive block base
}

// exclusive scan of counts + per-chunk degree histogram (bin = 63-min(deg,63), descending)
__global__ __launch_bounds__(256) void csr_scan3(const int* __restrict__ counts, const int* __restrict__ bsum,
                                                 int* __restrict__ offsets, int* __restrict__ cursor,
                                                 int* __restrict__ bhist) {
    __shared__ int sd[256];
    __shared__ int hist[64];
    int t = threadIdx.x, b = blockIdx.x;
    if (t < 64) hist[t] = 0;
    int idx = b * CHUNK + t;
    int v = (t < CHUNK && idx < N_NODES) ? counts[idx] : 0;
    sd[t] = v;
    __syncthreads();
    for (int d = 1; d < 256; d <<= 1) {
        int u = (t >= d) ? sd[t - d] : 0;
        __syncthreads();
        if (t >= d) sd[t] += u;
        __syncthreads();
    }
    if (t < CHUNK && idx < N_NODES) {
        int ex = bsum[b] + sd[t] - v;    // exclusive scan
        offsets[idx] = ex;
        cursor[idx]  = ex;
        atomicAdd(&hist[63 - min(v, 63)], 1);   // LDS atomic
    }
    __syncthreads();
    if (t < 64) bhist[b * 64 + t] = hist[t];
    if (b == 0 && t == 0) offsets[N_NODES] = EP;
}

__global__ void deg_scan(const int* __restrict__ bhist, int* __restrict__ pbase) {
    __shared__ int tot[64], base[64];
    int t = threadIdx.x;
    if (t < 64) {
        int s = 0;
        for (int b = 0; b < SCAN_BLOCKS; ++b) s += bhist[b * 64 + t];
        tot[t] = s;
    }
    __syncthreads();
    if (t == 0) {
        int run = 0;
        for (int k = 0; k < 64; ++k) { base[k] = run; run += tot[k]; }
    }
    __syncthreads();
    if (t < 64) {
        int run = base[t];
        for (int b = 0; b < SCAN_BLOCKS; ++b) { pbase[b * 64 + t] = run; run += bhist[b * 64 + t]; }
    }
}

// merged: blocks [0,SCAN_BLOCKS) place node_order; blocks [SCAN_BLOCKS,..) scatter CSR
__global__ __launch_bounds__(256) void place_scatter(const int* __restrict__ counts, const int* __restrict__ pbase,
                                                     int* __restrict__ node_order,
                                                     const int* __restrict__ ei, int* __restrict__ cursor,
                                                     int* __restrict__ csr_src) {
    int b = blockIdx.x;
    if (b < SCAN_BLOCKS) {
        __shared__ int cur[64];
        int t = threadIdx.x;
        if (t < 64) cur[t] = pbase[b * 64 + t];
        __syncthreads();
        int idx = b * CHUNK + t;
        if (t < CHUNK && idx < N_NODES) {
            int bin = 63 - min(counts[idx], 63);
            int p = atomicAdd(&cur[bin], 1);   // LDS atomic, block-local
            node_order[p] = idx;
        }
    } else {
        int t = (b - SCAN_BLOCKS) * 256 + threadIdx.x;
        if (t >= EP) return;
        int s, d; edge_sd(ei, t, s, d);
        int pos = atomicAdd(&cursor[d], 1);
        csr_src[pos] = s;
    }
}

// ---------------- MFMA GEMM (no LDS; A direct from L2-resident W; cvt_pk epilogue) ----------------
__global__ __launch_bounds__(256) void gemm_mfma(const ushort_t* __restrict__ xb,
                                                 const ushort_t* __restrict__ Wt,
                                                 ushort_t* __restrict__ xlr) {
    int t = threadIdx.x;
    int lane = t & 63, w = t >> 6;
    int ln = lane & 15, q = lane >> 4;
    int colq = blockIdx.y;
    int node = blockIdx.x * 64 + w * 16 + ln;
    int nclamp = node < N_NODES ? node : N_NODES - 1;
    const short8 b0 = *(const short8*)(xb + (size_t)nclamp * 64 + q * 8);
    const short8 b1 = *(const short8*)(xb + (size_t)nclamp * 64 + 32 + q * 8);
    const ushort_t* Wbase = Wt + (size_t)colq * 128 * 64;
#pragma unroll
    for (int ct = 0; ct < 8; ++ct) {
        int col = ct * 16 + ln;
        const short8 a0 = *(const short8*)(Wbase + col * 64 + q * 8);
        const short8 a1 = *(const short8*)(Wbase + col * 64 + 32 + q * 8);
        f32x4 acc = {0.f, 0.f, 0.f, 0.f};
        acc = __builtin_amdgcn_mfma_f32_16x16x32_bf16(a0, b0, acc, 0, 0, 0);
        acc = __builtin_amdgcn_mfma_f32_16x16x32_bf16(a1, b1, acc, 0, 0, 0);
        if (node < N_NODES) {
            uint_t lo = pack_bf2(acc[0], acc[1]);
            uint_t hi = pack_bf2(acc[2], acc[3]);
            *(uint2*)(xlr + (size_t)node * 1024 + colq * 128 + ct * 16 + q * 4) = make_uint2(lo, hi);
        }
    }
}

// ---------------- fused node kernel (packed-fp32 math) ----------------
// One wave per node (degree-sorted). lane = h*8 + i.
// leaky(t)=0.6t+0.4|t| -> a.leaky(v+r) = (0.6a).v + (0.4a).|v+r| + 0.6(a.r)
// the 0.6(a.r) term is edge-invariant per head -> cancels in softmax -> dropped.
__global__ __launch_bounds__(256) void node_fused(const float* __restrict__ x_in,
                                                  const ushort_t* __restrict__ xlr,
                                                  const float* __restrict__ att,
                                                  const int* __restrict__ offsets, const int* __restrict__ csr_src,
                                                  const int* __restrict__ node_order,
                                                  const float* __restrict__ bias, const float* __restrict__ gamma,
                                                  const float* __restrict__ beta, float* __restrict__ x_out,
                                                  ushort_t* __restrict__ xb_out) {
    int n = node_order[blockIdx.x * 4 + (threadIdx.x >> 6)];
    n = __builtin_amdgcn_readfirstlane(n);
    int lane = threadIdx.x & 63;
    int h = lane >> 3, i = lane & 7;
    int beg = __builtin_amdgcn_readfirstlane(offsets[n]);
    int end = __builtin_amdgcn_readfirstlane(offsets[n + 1]);
    int off = h * 64 + i * 8;

    // loop-invariants
    uint4 ru = *(const uint4*)(xlr + (size_t)n * 1024 + 512 + off);
    f32x2 rv0 = mkf2(ru.x), rv1 = mkf2(ru.y), rv2 = mkf2(ru.z), rv3 = mkf2(ru.w);
    const float4* pa = (const float4*)(att + h * 64 + i * 8);
    float4 aa = pa[0], ab = pa[1];
    f32x2 a0 = {aa.x, aa.y}, a1 = {aa.z, aa.w}, a2 = {ab.x, ab.y}, a3 = {ab.z, ab.w};
    f32x2 a60 = 0.6f * a0, a61 = 0.6f * a1, a62 = 0.6f * a2, a63 = 0.6f * a3;
    f32x2 a40 = 0.4f * a0, a41 = 0.4f * a1, a42 = 0.4f * a2, a43 = 0.4f * a3;

    float den = 0.f;
    f32x2 acc0 = {0.f, 0.f}, acc1 = {0.f, 0.f}, acc2 = {0.f, 0.f}, acc3 = {0.f, 0.f};

#define PROCESS(cur)                                                     \
    {                                                                    \
        f32x2 v0 = mkf2(cur.x), v1 = mkf2(cur.y),                        \
              v2 = mkf2(cur.z), v3 = mkf2(cur.w);                        \
        f32x2 p = a60 * v0;                                              \
        p = a61 * v1 + p;                                                \
        p = a62 * v2 + p;                                                \
        p = a63 * v3 + p;                                                \
        p = a40 * absf2(v0 + rv0) + p;                                   \
        p = a41 * absf2(v1 + rv1) + p;                                   \
        p = a42 * absf2(v2 + rv2) + p;                                   \
        p = a43 * absf2(v3 + rv3) + p;                                   \
        float pdot = p.x + p.y;                                          \
        pdot += __shfl_xor(pdot, 1);                                     \
        pdot += __shfl_xor(pdot, 2);                                     \
        pdot += __shfl_xor(pdot, 4);                                     \
        float wgt = __expf(pdot);                                        \
        den += wgt;                                                      \
        f32x2 wv = {wgt, wgt};                                           \
        acc0 = wv * v0 + acc0;                                           \
        acc1 = wv * v1 + acc1;                                           \
        acc2 = wv * v2 + acc2;                                           \
        acc3 = wv * v3 + acc3;                                           \
    }

    for (int base = beg; base < end; base += 64) {
        int idx = base + lane;
        int srcs = csr_src[idx < end ? idx : end - 1];   // coalesced batch load
        int cnt = min(64, end - base);
        int j = 0;
        for (; j + 8 <= cnt; j += 8) {
            uint4 q[8];
#pragma unroll
            for (int u = 0; u < 8; ++u) {
                int ss = __shfl(srcs, j + u);
                q[u] = *(const uint4*)(xlr + (size_t)ss * 1024 + off);
            }
#pragma unroll
            for (int u = 0; u < 8; ++u) PROCESS(q[u]);
        }
        for (; j < cnt; ++j) {
            int ss = __shfl(srcs, j);
            uint4 qq = *(const uint4*)(xlr + (size_t)ss * 1024 + off);
            PROCESS(qq);
        }
    }
#undef PROCESS

    // normalize per head (0.125 head-mean folded in), reduce over heads
    float invden = 0.125f / den;
    f32x2 iv = {invden, invden};
    acc0 *= iv; acc1 *= iv; acc2 *= iv; acc3 *= iv;
    float acc[8] = {acc0.x, acc0.y, acc1.x, acc1.y, acc2.x, acc2.y, acc3.x, acc3.y};
#pragma unroll
    for (int dm = 8; dm < 64; dm <<= 1) {
#pragma unroll
        for (int k2 = 0; k2 < 8; ++k2) acc[k2] += __shfl_xor(acc[k2], dm);
    }

    // bias + residual; LN stats across channels
    int cbase = i * 8;
    const float4* px = (const float4*)(x_in + n * 64 + cbase);
    float4 x0 = px[0], x1 = px[1];
    float xi[8] = {x0.x, x0.y, x0.z, x0.w, x1.x, x1.y, x1.z, x1.w};
    float v[8];
    float sum = 0.f, sq = 0.f;
#pragma unroll
    for (int k2 = 0; k2 < 8; ++k2) {
        float val = acc[k2] + bias[cbase + k2] + xi[k2];
        v[k2] = val; sum += val; sq += val * val;
    }
#pragma unroll
    for (int dm = 1; dm < 8; dm <<= 1) { sum += __shfl_xor(sum, dm); sq += __shfl_xor(sq, dm); }
    float mu   = sum * (1.0f / 64.0f);
    float var  = sq * (1.0f / 64.0f) - mu * mu;
    float rstd = rsqrtf(var + LN_EPS);

    if (h == 0) {
        float o[8];
#pragma unroll
        for (int k2 = 0; k2 < 8; ++k2) {
            float y = (v[k2] - mu) * rstd * gamma[cbase + k2] + beta[cbase + k2];
            o[k2] = fmaxf(y, 0.f);
        }
        float4* po = (float4*)(x_out + n * 64 + cbase);
        po[0] = make_float4(o[0], o[1], o[2], o[3]);
        po[1] = make_float4(o[4], o[5], o[6], o[7]);
        *(uint4*)(xb_out + (size_t)n * 64 + cbase) =
            make_uint4(pack_bf2(o[0], o[1]), pack_bf2(o[2], o[3]),
                       pack_bf2(o[4], o[5]), pack_bf2(o[6], o[7]));
    }
}

// ---------------- host ----------------

extern "C" void kernel_launch(void* const* d_in, const int* in_sizes, int n_in,
                              void* d_out, int out_size, void* d_ws, size_t ws_size,
                              hipStream_t stream) {
    const float* x     = (const float*)d_in[0];
    const float* Wl    = (const float*)d_in[1];
    const float* Wr    = (const float*)d_in[2];
    const float* att   = (const float*)d_in[3];
    const float* b     = (const float*)d_in[4];
    const float* gamma = (const float*)d_in[5];
    const float* beta  = (const float*)d_in[6];
    const int*   ei    = (const int*)d_in[7];
    float* out = (float*)d_out;

    ushort_t* xlr = (ushort_t*)d_ws;                       // N*1024 bf16
    ushort_t* xb  = xlr + (size_t)N_NODES * 1024;          // PAD_N*64 bf16
    ushort_t* Wt  = xb + (size_t)PAD_N * 64;               // 3*1024*64 bf16
    int* counts     = (int*)(Wt + 3 * 1024 * 64);          // PAD_N
    int* offsets    = counts + PAD_N;                      // PAD_N (N+1 used)
    int* cursor     = offsets + PAD_N;                     // PAD_N
    int* bsum       = cursor + PAD_N;                      // 256
    int* node_order = bsum + 256;                          // PAD_N
    int* bhist      = node_order + PAD_N;                  // 256*64
    int* pbase      = bhist + SCAN_BLOCKS * 64;            // 256*64
    int* csr_src    = pbase + SCAN_BLOCKS * 64;            // EP

    hipMemsetAsync(counts, 0, N_NODES * sizeof(int), stream);

    // setup: edge histogram + x/W bf16 conversion in one launch
    int setup_threads = EP + N_NODES * 64 + 3 * 1024 * 64;
    setup_all<<<(setup_threads + 255) / 256, 256, 0, stream>>>(ei, counts, x, Wl, Wr, xb, Wt);

    csr_scan1<<<SCAN_BLOCKS, 256, 0, stream>>>(counts, bsum);
    csr_scan2<<<1, 256, 0, stream>>>(bsum);
    csr_scan3<<<SCAN_BLOCKS, 256, 0, stream>>>(counts, bsum, offsets, cursor, bhist);
    deg_scan <<<1, 256, 0, stream>>>(bhist, pbase);
    int eb = (EP + 255) / 256;
    place_scatter<<<SCAN_BLOCKS + eb, 256, 0, stream>>>(counts, pbase, node_order, ei, cursor, csr_src);

    const float* xin = x;
    dim3 ggrid(PAD_N / 64, 8);
    for (int l = 0; l < 3; ++l) {
        gemm_mfma <<<ggrid, 256, 0, stream>>>(xb, Wt + (size_t)l * 1024 * 64, xlr);
        node_fused<<<N_NODES / 4, 256, 0, stream>>>(xin, xlr, att + l * (H * D), offsets, csr_src,
                                                    node_order, b + l * D, gamma + l * D, beta + l * D,
                                                    out, xb);
        xin = out;
    }
}

// Round 9
// 475.954 us; speedup vs baseline: 1.1503x; 1.1503x over previous
//
#include <hip/hip_runtime.h>

#define N_NODES 50000
#define N_EDGES 400000
#define EP (N_EDGES + N_NODES)   // 450000 edges incl. self-loops
#define D 64
#define H 8
#define NEG_SLOPE 0.2f
#define LN_EPS 1e-5f
#define CHUNK 196
#define SCAN_BLOCKS 256
#define PAD_N 50048

typedef unsigned short ushort_t;
typedef unsigned int uint_t;
typedef __attribute__((ext_vector_type(8))) short short8;
typedef __attribute__((ext_vector_type(4))) float f32x4;
typedef __attribute__((ext_vector_type(2))) float f32x2;

#if defined(__has_builtin)
#if __has_builtin(__builtin_amdgcn_cvt_pk_bf16_f32)
#define HAVE_CVT_PK_BF16 1
#endif
#endif

__device__ __forceinline__ ushort_t f2bf(float f) {
    uint_t u = __float_as_uint(f);
    u += 0x7fffu + ((u >> 16) & 1u);          // round-to-nearest-even
    return (ushort_t)(u >> 16);
}
// pack two f32 -> packed bf16 pair (lo = a, hi = b)
__device__ __forceinline__ uint_t pack_bf2(float a, float b) {
#ifdef HAVE_CVT_PK_BF16
    typedef __attribute__((ext_vector_type(2))) __bf16 bf16x2_t;
    bf16x2_t v = __builtin_amdgcn_cvt_pk_bf16_f32(a, b);
    uint_t r;
    __builtin_memcpy(&r, &v, 4);
    return r;
#else
    return (uint_t)f2bf(a) | ((uint_t)f2bf(b) << 16);
#endif
}
// unpack a packed pair of bf16 (one u32) -> f32x2 {lo, hi}
__device__ __forceinline__ f32x2 mkf2(uint_t u) {
    f32x2 r;
    r.x = __uint_as_float(u << 16);
    r.y = __uint_as_float(u & 0xffff0000u);
    return r;
}
__device__ __forceinline__ f32x2 absf2(f32x2 a) {
    f32x2 r;
    r.x = __uint_as_float(__float_as_uint(a.x) & 0x7fffffffu);
    r.y = __uint_as_float(__float_as_uint(a.y) & 0x7fffffffu);
    return r;
}

// decode edge id -> (src, dst); ids >= N_EDGES are self-loops
__device__ __forceinline__ void edge_sd(const int* __restrict__ ei, int eid, int& s, int& d) {
    if (eid < N_EDGES) { s = ei[eid]; d = ei[N_EDGES + eid]; }
    else               { s = d = eid - N_EDGES; }
}

// ---------------- setup: edge histogram + bf16 conversions (one kernel) ----------------

__global__ __launch_bounds__(256) void setup_all(const int* __restrict__ ei, int* __restrict__ counts,
                                                 const float* __restrict__ x,
                                                 const float* __restrict__ Wl, const float* __restrict__ Wr,
                                                 ushort_t* __restrict__ xb, ushort_t* __restrict__ Wt) {
    int t = blockIdx.x * 256 + threadIdx.x;
    if (t < EP) {
        int s, d; edge_sd(ei, t, s, d);
        atomicAdd(&counts[d], 1);
        return;
    }
    t -= EP;
    if (t < N_NODES * 64) { xb[t] = f2bf(x[t]); return; }
    t -= N_NODES * 64;
    if (t >= 3 * 1024 * 64) return;
    int l = t >> 16, rem = t & 65535, col = rem >> 6, k = rem & 63;
    float v = (col < 512) ? Wl[((size_t)l * 64 + k) * 512 + col]
                          : Wr[((size_t)l * 64 + k) * 512 + (col - 512)];
    Wt[t] = f2bf(v);
}

// ---------------- CSR scans ----------------

__global__ __launch_bounds__(256) void csr_scan1(const int* __restrict__ counts, int* __restrict__ bsum) {
    __shared__ int sd[256];
    int t = threadIdx.x, b = blockIdx.x;
    int idx = b * CHUNK + t;
    sd[t] = (t < CHUNK && idx < N_NODES) ? counts[idx] : 0;
    __syncthreads();
    for (int d = 128; d > 0; d >>= 1) {
        if (t < d) sd[t] += sd[t + d];
        __syncthreads();
    }
    if (t == 0) bsum[b] = sd[0];
}

__global__ __launch_bounds__(256) void csr_scan2(int* __restrict__ bsum) {
    __shared__ int sd[256];
    int t = threadIdx.x;
    sd[t] = bsum[t];
    __syncthreads();
    for (int d = 1; d < 256; d <<= 1) {
        int v = (t >= d) ? sd[t - d] : 0;
        __syncthreads();
        if (t >= d) sd[t] += v;
        __syncthreads();
    }
    bsum[t] = (t > 0) ? sd[t - 1] : 0;   // exclusive block base
}

// exclusive scan of counts + per-chunk degree histogram (bin = 63-min(deg,63), descending)
__global__ __launch_bounds__(256) void csr_scan3(const int* __restrict__ counts, const int* __restrict__ bsum,
                                                 int* __restrict__ offsets, int* __restrict__ cursor,
                                                 int* __restrict__ bhist) {
    __shared__ int sd[256];
    __shared__ int hist[64];
    int t = threadIdx.x, b = blockIdx.x;
    if (t < 64) hist[t] = 0;
    int idx = b * CHUNK + t;
    int v = (t < CHUNK && idx < N_NODES) ? counts[idx] : 0;
    sd[t] = v;
    __syncthreads();
    for (int d = 1; d < 256; d <<= 1) {
        int u = (t >= d) ? sd[t - d] : 0;
        __syncthreads();
        if (t >= d) sd[t] += u;
        __syncthreads();
    }
    if (t < CHUNK && idx < N_NODES) {
        int ex = bsum[b] + sd[t] - v;    // exclusive scan
        offsets[idx] = ex;
        cursor[idx]  = ex;
        atomicAdd(&hist[63 - min(v, 63)], 1);   // LDS atomic
    }
    __syncthreads();
    if (t < 64) bhist[b * 64 + t] = hist[t];
    if (b == 0 && t == 0) offsets[N_NODES] = EP;
}

__global__ void deg_scan(const int* __restrict__ bhist, int* __restrict__ pbase) {
    __shared__ int tot[64], base[64];
    int t = threadIdx.x;
    if (t < 64) {
        int s = 0;
        for (int b = 0; b < SCAN_BLOCKS; ++b) s += bhist[b * 64 + t];
        tot[t] = s;
    }
    __syncthreads();
    if (t == 0) {
        int run = 0;
        for (int k = 0; k < 64; ++k) { base[k] = run; run += tot[k]; }
    }
    __syncthreads();
    if (t < 64) {
        int run = base[t];
        for (int b = 0; b < SCAN_BLOCKS; ++b) { pbase[b * 64 + t] = run; run += bhist[b * 64 + t]; }
    }
}

// merged: blocks [0,SCAN_BLOCKS) place node_order; blocks [SCAN_BLOCKS,..) scatter CSR
__global__ __launch_bounds__(256) void place_scatter(const int* __restrict__ counts, const int* __restrict__ pbase,
                                                     int* __restrict__ node_order,
                                                     const int* __restrict__ ei, int* __restrict__ cursor,
                                                     int* __restrict__ csr_src) {
    int b = blockIdx.x;
    if (b < SCAN_BLOCKS) {
        __shared__ int cur[64];
        int t = threadIdx.x;
        if (t < 64) cur[t] = pbase[b * 64 + t];
        __syncthreads();
        int idx = b * CHUNK + t;
        if (t < CHUNK && idx < N_NODES) {
            int bin = 63 - min(counts[idx], 63);
            int p = atomicAdd(&cur[bin], 1);   // LDS atomic, block-local
            node_order[p] = idx;
        }
    } else {
        int t = (b - SCAN_BLOCKS) * 256 + threadIdx.x;
        if (t >= EP) return;
        int s, d; edge_sd(ei, t, s, d);
        int pos = atomicAdd(&cursor[d], 1);
        csr_src[pos] = s;
    }
}

// ---------------- MFMA GEMM (LDS-staged W — the R7 known-good structure; cvt_pk epilogue) ----------------
// grid (782, 8): 64 nodes x 128 cols per block. W slice staged in padded LDS (once per block,
// amortized over 4 waves; avoids re-paying L2 latency inside the MFMA loop).
__global__ __launch_bounds__(256) void gemm_mfma(const ushort_t* __restrict__ xb,
                                                 const ushort_t* __restrict__ Wt,
                                                 ushort_t* __restrict__ xlr) {
    __shared__ ushort_t sW[128 * 72];    // 128 cols x 64 k, rows padded to 72 shorts
    int t = threadIdx.x;
    int colq = blockIdx.y;
    const ushort_t* Wg = Wt + (size_t)colq * 128 * 64;
    {
        int col = t >> 1, half = t & 1;
        const uint4* g = (const uint4*)(Wg + col * 64 + half * 32);
        uint4* l = (uint4*)(sW + col * 72 + half * 32);
        l[0] = g[0]; l[1] = g[1]; l[2] = g[2]; l[3] = g[3];
    }
    __syncthreads();
    int lane = t & 63, w = t >> 6;
    int ln = lane & 15, q = lane >> 4;
    int node = blockIdx.x * 64 + w * 16 + ln;
    int nclamp = node < N_NODES ? node : N_NODES - 1;
    const short8 b0 = *(const short8*)(xb + (size_t)nclamp * 64 + q * 8);
    const short8 b1 = *(const short8*)(xb + (size_t)nclamp * 64 + 32 + q * 8);
#pragma unroll
    for (int ct = 0; ct < 8; ++ct) {
        const short8 a0 = *(const short8*)(sW + (ct * 16 + ln) * 72 + q * 8);
        const short8 a1 = *(const short8*)(sW + (ct * 16 + ln) * 72 + 32 + q * 8);
        f32x4 acc = {0.f, 0.f, 0.f, 0.f};
        acc = __builtin_amdgcn_mfma_f32_16x16x32_bf16(a0, b0, acc, 0, 0, 0);
        acc = __builtin_amdgcn_mfma_f32_16x16x32_bf16(a1, b1, acc, 0, 0, 0);
        if (node < N_NODES) {
            uint_t lo = pack_bf2(acc[0], acc[1]);
            uint_t hi = pack_bf2(acc[2], acc[3]);
            *(uint2*)(xlr + (size_t)node * 1024 + colq * 128 + ct * 16 + q * 4) = make_uint2(lo, hi);
        }
    }
}

// ---------------- fused node kernel (packed-fp32 math) ----------------
// One wave per node (degree-sorted). lane = h*8 + i.
// leaky(t)=0.6t+0.4|t| -> a.leaky(v+r) = (0.6a).v + (0.4a).|v+r| + 0.6(a.r)
// the 0.6(a.r) term is edge-invariant per head -> cancels in softmax -> dropped.
__global__ __launch_bounds__(256) void node_fused(const float* __restrict__ x_in,
                                                  const ushort_t* __restrict__ xlr,
                                                  const float* __restrict__ att,
                                                  const int* __restrict__ offsets, const int* __restrict__ csr_src,
                                                  const int* __restrict__ node_order,
                                                  const float* __restrict__ bias, const float* __restrict__ gamma,
                                                  const float* __restrict__ beta, float* __restrict__ x_out,
                                                  ushort_t* __restrict__ xb_out) {
    int n = node_order[blockIdx.x * 4 + (threadIdx.x >> 6)];
    n = __builtin_amdgcn_readfirstlane(n);
    int lane = threadIdx.x & 63;
    int h = lane >> 3, i = lane & 7;
    int beg = __builtin_amdgcn_readfirstlane(offsets[n]);
    int end = __builtin_amdgcn_readfirstlane(offsets[n + 1]);
    int off = h * 64 + i * 8;

    // loop-invariants
    uint4 ru = *(const uint4*)(xlr + (size_t)n * 1024 + 512 + off);
    f32x2 rv0 = mkf2(ru.x), rv1 = mkf2(ru.y), rv2 = mkf2(ru.z), rv3 = mkf2(ru.w);
    const float4* pa = (const float4*)(att + h * 64 + i * 8);
    float4 aa = pa[0], ab = pa[1];
    f32x2 a0 = {aa.x, aa.y}, a1 = {aa.z, aa.w}, a2 = {ab.x, ab.y}, a3 = {ab.z, ab.w};
    f32x2 a60 = 0.6f * a0, a61 = 0.6f * a1, a62 = 0.6f * a2, a63 = 0.6f * a3;
    f32x2 a40 = 0.4f * a0, a41 = 0.4f * a1, a42 = 0.4f * a2, a43 = 0.4f * a3;

    float den = 0.f;
    f32x2 acc0 = {0.f, 0.f}, acc1 = {0.f, 0.f}, acc2 = {0.f, 0.f}, acc3 = {0.f, 0.f};

#define PROCESS(cur)                                                     \
    {                                                                    \
        f32x2 v0 = mkf2(cur.x), v1 = mkf2(cur.y),                        \
              v2 = mkf2(cur.z), v3 = mkf2(cur.w);                        \
        f32x2 p = a60 * v0;                                              \
        p = a61 * v1 + p;                                                \
        p = a62 * v2 + p;                                                \
        p = a63 * v3 + p;                                                \
        p = a40 * absf2(v0 + rv0) + p;                                   \
        p = a41 * absf2(v1 + rv1) + p;                                   \
        p = a42 * absf2(v2 + rv2) + p;                                   \
        p = a43 * absf2(v3 + rv3) + p;                                   \
        float pdot = p.x + p.y;                                          \
        pdot += __shfl_xor(pdot, 1);                                     \
        pdot += __shfl_xor(pdot, 2);                                     \
        pdot += __shfl_xor(pdot, 4);                                     \
        float wgt = __expf(pdot);                                        \
        den += wgt;                                                      \
        f32x2 wv = {wgt, wgt};                                           \
        acc0 = wv * v0 + acc0;                                           \
        acc1 = wv * v1 + acc1;                                           \
        acc2 = wv * v2 + acc2;                                           \
        acc3 = wv * v3 + acc3;                                           \
    }

    for (int base = beg; base < end; base += 64) {
        int idx = base + lane;
        int srcs = csr_src[idx < end ? idx : end - 1];   // coalesced batch load
        int cnt = min(64, end - base);
        int j = 0;
        for (; j + 8 <= cnt; j += 8) {
            uint4 q[8];
#pragma unroll
            for (int u = 0; u < 8; ++u) {
                int ss = __shfl(srcs, j + u);
                q[u] = *(const uint4*)(xlr + (size_t)ss * 1024 + off);
            }
#pragma unroll
            for (int u = 0; u < 8; ++u) PROCESS(q[u]);
        }
        for (; j < cnt; ++j) {
            int ss = __shfl(srcs, j);
            uint4 qq = *(const uint4*)(xlr + (size_t)ss * 1024 + off);
            PROCESS(qq);
        }
    }
#undef PROCESS

    // normalize per head (0.125 head-mean folded in), reduce over heads
    float invden = 0.125f / den;
    f32x2 iv = {invden, invden};
    acc0 *= iv; acc1 *= iv; acc2 *= iv; acc3 *= iv;
    float acc[8] = {acc0.x, acc0.y, acc1.x, acc1.y, acc2.x, acc2.y, acc3.x, acc3.y};
#pragma unroll
    for (int dm = 8; dm < 64; dm <<= 1) {
#pragma unroll
        for (int k2 = 0; k2 < 8; ++k2) acc[k2] += __shfl_xor(acc[k2], dm);
    }

    // bias + residual; LN stats across channels
    int cbase = i * 8;
    const float4* px = (const float4*)(x_in + n * 64 + cbase);
    float4 x0 = px[0], x1 = px[1];
    float xi[8] = {x0.x, x0.y, x0.z, x0.w, x1.x, x1.y, x1.z, x1.w};
    float v[8];
    float sum = 0.f, sq = 0.f;
#pragma unroll
    for (int k2 = 0; k2 < 8; ++k2) {
        float val = acc[k2] + bias[cbase + k2] + xi[k2];
        v[k2] = val; sum += val; sq += val * val;
    }
#pragma unroll
    for (int dm = 1; dm < 8; dm <<= 1) { sum += __shfl_xor(sum, dm); sq += __shfl_xor(sq, dm); }
    float mu   = sum * (1.0f / 64.0f);
    float var  = sq * (1.0f / 64.0f) - mu * mu;
    float rstd = rsqrtf(var + LN_EPS);

    if (h == 0) {
        float o[8];
#pragma unroll
        for (int k2 = 0; k2 < 8; ++k2) {
            float y = (v[k2] - mu) * rstd * gamma[cbase + k2] + beta[cbase + k2];
            o[k2] = fmaxf(y, 0.f);
        }
        float4* po = (float4*)(x_out + n * 64 + cbase);
        po[0] = make_float4(o[0], o[1], o[2], o[3]);
        po[1] = make_float4(o[4], o[5], o[6], o[7]);
        *(uint4*)(xb_out + (size_t)n * 64 + cbase) =
            make_uint4(pack_bf2(o[0], o[1]), pack_bf2(o[2], o[3]),
                       pack_bf2(o[4], o[5]), pack_bf2(o[6], o[7]));
    }
}

// ---------------- host ----------------

extern "C" void kernel_launch(void* const* d_in, const int* in_sizes, int n_in,
                              void* d_out, int out_size, void* d_ws, size_t ws_size,
                              hipStream_t stream) {
    const float* x     = (const float*)d_in[0];
    const float* Wl    = (const float*)d_in[1];
    const float* Wr    = (const float*)d_in[2];
    const float* att   = (const float*)d_in[3];
    const float* b     = (const float*)d_in[4];
    const float* gamma = (const float*)d_in[5];
    const float* beta  = (const float*)d_in[6];
    const int*   ei    = (const int*)d_in[7];
    float* out = (float*)d_out;

    ushort_t* xlr = (ushort_t*)d_ws;                       // N*1024 bf16
    ushort_t* xb  = xlr + (size_t)N_NODES * 1024;          // PAD_N*64 bf16
    ushort_t* Wt  = xb + (size_t)PAD_N * 64;               // 3*1024*64 bf16
    int* counts     = (int*)(Wt + 3 * 1024 * 64);          // PAD_N
    int* offsets    = counts + PAD_N;                      // PAD_N (N+1 used)
    int* cursor     = offsets + PAD_N;                     // PAD_N
    int* bsum       = cursor + PAD_N;                      // 256
    int* node_order = bsum + 256;                          // PAD_N
    int* bhist      = node_order + PAD_N;                  // 256*64
    int* pbase      = bhist + SCAN_BLOCKS * 64;            // 256*64
    int* csr_src    = pbase + SCAN_BLOCKS * 64;            // EP

    hipMemsetAsync(counts, 0, N_NODES * sizeof(int), stream);

    // setup: edge histogram + x/W bf16 conversion in one launch
    int setup_threads = EP + N_NODES * 64 + 3 * 1024 * 64;
    setup_all<<<(setup_threads + 255) / 256, 256, 0, stream>>>(ei, counts, x, Wl, Wr, xb, Wt);

    csr_scan1<<<SCAN_BLOCKS, 256, 0, stream>>>(counts, bsum);
    csr_scan2<<<1, 256, 0, stream>>>(bsum);
    csr_scan3<<<SCAN_BLOCKS, 256, 0, stream>>>(counts, bsum, offsets, cursor, bhist);
    deg_scan <<<1, 256, 0, stream>>>(bhist, pbase);
    int eb = (EP + 255) / 256;
    place_scatter<<<SCAN_BLOCKS + eb, 256, 0, stream>>>(counts, pbase, node_order, ei, cursor, csr_src);

    const float* xin = x;
    dim3 ggrid(PAD_N / 64, 8);
    for (int l = 0; l < 3; ++l) {
        gemm_mfma <<<ggrid, 256, 0, stream>>>(xb, Wt + (size_t)l * 1024 * 64, xlr);
        node_fused<<<N_NODES / 4, 256, 0, stream>>>(xin, xlr, att + l * (H * D), offsets, csr_src,
                                                    node_order, b + l * D, gamma + l * D, beta + l * D,
                                                    out, xb);
        xin = out;
    }
}

// Round 10
// 466.420 us; speedup vs baseline: 1.1738x; 1.0204x over previous
//
#include <hip/hip_runtime.h>

#define N_NODES 50000
#define N_EDGES 400000
#define EP (N_EDGES + N_NODES)   // 450000 edges incl. self-loops
#define D 64
#define H 8
#define NEG_SLOPE 0.2f
#define LN_EPS 1e-5f
#define CHUNK 196
#define SCAN_BLOCKS 256
#define PAD_N 50048
#define GEMM_BLOCKS (782 * 8)    // PAD_N/64 x 8 col-quarters

typedef unsigned short ushort_t;
typedef unsigned int uint_t;
typedef __attribute__((ext_vector_type(8))) short short8;
typedef __attribute__((ext_vector_type(4))) float f32x4;
typedef __attribute__((ext_vector_type(2))) float f32x2;

#if defined(__has_builtin)
#if __has_builtin(__builtin_amdgcn_cvt_pk_bf16_f32)
#define HAVE_CVT_PK_BF16 1
#endif
#endif

__device__ __forceinline__ ushort_t f2bf(float f) {
    uint_t u = __float_as_uint(f);
    u += 0x7fffu + ((u >> 16) & 1u);          // round-to-nearest-even
    return (ushort_t)(u >> 16);
}
__device__ __forceinline__ uint_t pack_bf2(float a, float b) {
#ifdef HAVE_CVT_PK_BF16
    typedef __attribute__((ext_vector_type(2))) __bf16 bf16x2_t;
    bf16x2_t v = __builtin_amdgcn_cvt_pk_bf16_f32(a, b);
    uint_t r;
    __builtin_memcpy(&r, &v, 4);
    return r;
#else
    return (uint_t)f2bf(a) | ((uint_t)f2bf(b) << 16);
#endif
}
__device__ __forceinline__ f32x2 mkf2(uint_t u) {
    f32x2 r;
    r.x = __uint_as_float(u << 16);
    r.y = __uint_as_float(u & 0xffff0000u);
    return r;
}
__device__ __forceinline__ f32x2 absf2(f32x2 a) {
    f32x2 r;
    r.x = __uint_as_float(__float_as_uint(a.x) & 0x7fffffffu);
    r.y = __uint_as_float(__float_as_uint(a.y) & 0x7fffffffu);
    return r;
}

// cross-lane reduce helpers: DPP for xor1/xor2/xor8 (pure VALU), ds_swizzle for xor4/xor16
__device__ __forceinline__ float xor1_dpp(float x) {   // quad_perm [1,0,3,2]
    int i = __float_as_int(x);
    return __int_as_float(__builtin_amdgcn_update_dpp(i, i, 0xB1, 0xF, 0xF, 1));
}
__device__ __forceinline__ float xor2_dpp(float x) {   // quad_perm [2,3,0,1]
    int i = __float_as_int(x);
    return __int_as_float(__builtin_amdgcn_update_dpp(i, i, 0x4E, 0xF, 0xF, 1));
}
__device__ __forceinline__ float xor8_dpp(float x) {   // ROW_ROR:8 == lane^8 within 16-row
    int i = __float_as_int(x);
    return __int_as_float(__builtin_amdgcn_update_dpp(i, i, 0x128, 0xF, 0xF, 1));
}
__device__ __forceinline__ float xor4_swz(float x) {   // ds_swizzle xor 4
    return __int_as_float(__builtin_amdgcn_ds_swizzle(__float_as_int(x), 0x101F));
}
__device__ __forceinline__ float xor16_swz(float x) {  // ds_swizzle xor 16
    return __int_as_float(__builtin_amdgcn_ds_swizzle(__float_as_int(x), 0x401F));
}

// decode edge id -> (src, dst); ids >= N_EDGES are self-loops
__device__ __forceinline__ void edge_sd(const int* __restrict__ ei, int eid, int& s, int& d) {
    if (eid < N_EDGES) { s = ei[eid]; d = ei[N_EDGES + eid]; }
    else               { s = d = eid - N_EDGES; }
}

// ---------------- setup: edge histogram + bf16 conversions (one kernel) ----------------

__global__ __launch_bounds__(256) void setup_all(const int* __restrict__ ei, int* __restrict__ counts,
                                                 const float* __restrict__ x,
                                                 const float* __restrict__ Wl, const float* __restrict__ Wr,
                                                 ushort_t* __restrict__ xb, ushort_t* __restrict__ Wt) {
    int t = blockIdx.x * 256 + threadIdx.x;
    if (t < EP) {
        int s, d; edge_sd(ei, t, s, d);
        atomicAdd(&counts[d], 1);
        return;
    }
    t -= EP;
    if (t < N_NODES * 64) { xb[t] = f2bf(x[t]); return; }
    t -= N_NODES * 64;
    if (t >= 3 * 1024 * 64) return;
    int l = t >> 16, rem = t & 65535, col = rem >> 6, k = rem & 63;
    float v = (col < 512) ? Wl[((size_t)l * 64 + k) * 512 + col]
                          : Wr[((size_t)l * 64 + k) * 512 + (col - 512)];
    Wt[t] = f2bf(v);
}

// ---------------- CSR scans + degree sort (restructured, no serial deg_scan) ----------------

// per-chunk sum of counts + per-chunk degree histogram (bin = 63-min(deg,63), descending)
__global__ __launch_bounds__(256) void csr_scan1(const int* __restrict__ counts, int* __restrict__ bsum,
                                                 int* __restrict__ bhist) {
    __shared__ int sd[256];
    __shared__ int hist[64];
    int t = threadIdx.x, b = blockIdx.x;
    if (t < 64) hist[t] = 0;
    int idx = b * CHUNK + t;
    int v = (t < CHUNK && idx < N_NODES) ? counts[idx] : 0;
    sd[t] = v;
    __syncthreads();
    if (t < CHUNK && idx < N_NODES) atomicAdd(&hist[63 - min(v, 63)], 1);
    for (int d = 128; d > 0; d >>= 1) {
        __syncthreads();
        if (t < d) sd[t] += sd[t + d];
    }
    __syncthreads();
    if (t == 0) bsum[b] = sd[0];
    if (t < 64) bhist[b * 64 + t] = hist[t];
}

// single block: exclusive scan of bsum (256) + pbase[b][k] from bhist (parallel two-pass)
__global__ __launch_bounds__(256) void csr_scan2(int* __restrict__ bsum,
                                                 const int* __restrict__ bhist, int* __restrict__ pbase) {
    __shared__ int sd[256];
    __shared__ int sg[64 * 4];   // per-(bin, group) partial sums
    __shared__ int base[64];
    int t = threadIdx.x;
    // part A: bsum exclusive scan
    sd[t] = bsum[t];
    __syncthreads();
    for (int d = 1; d < 256; d <<= 1) {
        int v = (t >= d) ? sd[t - d] : 0;
        __syncthreads();
        if (t >= d) sd[t] += v;
        __syncthreads();
    }
    bsum[t] = (t > 0) ? sd[t - 1] : 0;

    // part B: pbase. thread t = (k = t&63, g = t>>6); group g covers b in [64g, 64g+64)
    int k = t & 63, g = t >> 6;
    int s = 0;
    for (int j = 0; j < 64; ++j) s += bhist[(g * 64 + j) * 64 + k];   // coalesced over k
    sg[k * 4 + g] = s;
    __syncthreads();
    if (t == 0) {   // exclusive bin bases over k (descending-degree order)
        int run = 0;
        for (int kk = 0; kk < 64; ++kk) {
            base[kk] = run;
            run += sg[kk * 4 + 0] + sg[kk * 4 + 1] + sg[kk * 4 + 2] + sg[kk * 4 + 3];
        }
    }
    __syncthreads();
    int run = base[k];
    for (int gg = 0; gg < g; ++gg) run += sg[k * 4 + gg];
    for (int j = 0; j < 64; ++j) {
        int b = g * 64 + j;
        pbase[b * 64 + k] = run;
        run += bhist[b * 64 + k];
    }
}

// exclusive scan of counts -> offsets/cursor, + place node_order (descending degree)
__global__ __launch_bounds__(256) void csr_scan3(const int* __restrict__ counts, const int* __restrict__ bsum,
                                                 int* __restrict__ offsets, int* __restrict__ cursor,
                                                 const int* __restrict__ pbase, int* __restrict__ node_order) {
    __shared__ int sd[256];
    __shared__ int cur[64];
    int t = threadIdx.x, b = blockIdx.x;
    if (t < 64) cur[t] = pbase[b * 64 + t];
    int idx = b * CHUNK + t;
    int v = (t < CHUNK && idx < N_NODES) ? counts[idx] : 0;
    sd[t] = v;
    __syncthreads();
    for (int d = 1; d < 256; d <<= 1) {
        int u = (t >= d) ? sd[t - d] : 0;
        __syncthreads();
        if (t >= d) sd[t] += u;
        __syncthreads();
    }
    if (t < CHUNK && idx < N_NODES) {
        int ex = bsum[b] + sd[t] - v;    // exclusive scan
        offsets[idx] = ex;
        cursor[idx]  = ex;
        int bin = 63 - min(v, 63);
        int p = atomicAdd(&cur[bin], 1); // LDS atomic, block-local
        node_order[p] = idx;
    }
    if (b == 0 && t == 0) offsets[N_NODES] = EP;
}

// ---------------- MFMA GEMM (LDS-staged W), with optional CSR-scatter blocks appended ----------------
// blocks [0, GEMM_BLOCKS): gemm (bx = b%782, colq = b/782). blocks >= GEMM_BLOCKS: edge scatter.
__global__ __launch_bounds__(256) void gemm_mfma(const ushort_t* __restrict__ xb,
                                                 const ushort_t* __restrict__ Wt,
                                                 ushort_t* __restrict__ xlr,
                                                 const int* __restrict__ ei, int* __restrict__ cursor,
                                                 int* __restrict__ csr_src) {
    __shared__ ushort_t sW[128 * 72];    // 128 cols x 64 k, rows padded to 72 shorts
    int b = blockIdx.x;
    if (b >= GEMM_BLOCKS) {              // scatter part (layer-0 launch only)
        int t = (b - GEMM_BLOCKS) * 256 + threadIdx.x;
        if (t >= EP) return;
        int s, d; edge_sd(ei, t, s, d);
        int pos = atomicAdd(&cursor[d], 1);
        csr_src[pos] = s;
        return;
    }
    int colq = b / 782;
    int bx = b - colq * 782;
    int t = threadIdx.x;
    const ushort_t* Wg = Wt + (size_t)colq * 128 * 64;
    {
        int col = t >> 1, half = t & 1;
        const uint4* g = (const uint4*)(Wg + col * 64 + half * 32);
        uint4* l = (uint4*)(sW + col * 72 + half * 32);
        l[0] = g[0]; l[1] = g[1]; l[2] = g[2]; l[3] = g[3];
    }
    __syncthreads();
    int lane = t & 63, w = t >> 6;
    int ln = lane & 15, q = lane >> 4;
    int node = bx * 64 + w * 16 + ln;
    int nclamp = node < N_NODES ? node : N_NODES - 1;
    const short8 b0 = *(const short8*)(xb + (size_t)nclamp * 64 + q * 8);
    const short8 b1 = *(const short8*)(xb + (size_t)nclamp * 64 + 32 + q * 8);
#pragma unroll
    for (int ct = 0; ct < 8; ++ct) {
        const short8 a0 = *(const short8*)(sW + (ct * 16 + ln) * 72 + q * 8);
        const short8 a1 = *(const short8*)(sW + (ct * 16 + ln) * 72 + 32 + q * 8);
        f32x4 acc = {0.f, 0.f, 0.f, 0.f};
        acc = __builtin_amdgcn_mfma_f32_16x16x32_bf16(a0, b0, acc, 0, 0, 0);
        acc = __builtin_amdgcn_mfma_f32_16x16x32_bf16(a1, b1, acc, 0, 0, 0);
        if (node < N_NODES) {
            uint_t lo = pack_bf2(acc[0], acc[1]);
            uint_t hi = pack_bf2(acc[2], acc[3]);
            *(uint2*)(xlr + (size_t)node * 1024 + colq * 128 + ct * 16 + q * 4) = make_uint2(lo, hi);
        }
    }
}

// ---------------- fused node kernel (packed-fp32 math, DPP reduces) ----------------
__global__ __launch_bounds__(256) void node_fused(const float* __restrict__ x_in,
                                                  const ushort_t* __restrict__ xlr,
                                                  const float* __restrict__ att,
                                                  const int* __restrict__ offsets, const int* __restrict__ csr_src,
                                                  const int* __restrict__ node_order,
                                                  const float* __restrict__ bias, const float* __restrict__ gamma,
                                                  const float* __restrict__ beta, float* __restrict__ x_out,
                                                  ushort_t* __restrict__ xb_out) {
    int n = node_order[blockIdx.x * 4 + (threadIdx.x >> 6)];
    n = __builtin_amdgcn_readfirstlane(n);
    int lane = threadIdx.x & 63;
    int h = lane >> 3, i = lane & 7;
    int beg = __builtin_amdgcn_readfirstlane(offsets[n]);
    int end = __builtin_amdgcn_readfirstlane(offsets[n + 1]);
    int off = h * 64 + i * 8;

    // loop-invariants
    uint4 ru = *(const uint4*)(xlr + (size_t)n * 1024 + 512 + off);
    f32x2 rv0 = mkf2(ru.x), rv1 = mkf2(ru.y), rv2 = mkf2(ru.z), rv3 = mkf2(ru.w);
    const float4* pa = (const float4*)(att + h * 64 + i * 8);
    float4 aa = pa[0], ab = pa[1];
    f32x2 a0 = {aa.x, aa.y}, a1 = {aa.z, aa.w}, a2 = {ab.x, ab.y}, a3 = {ab.z, ab.w};
    f32x2 a60 = 0.6f * a0, a61 = 0.6f * a1, a62 = 0.6f * a2, a63 = 0.6f * a3;
    f32x2 a40 = 0.4f * a0, a41 = 0.4f * a1, a42 = 0.4f * a2, a43 = 0.4f * a3;

    float den = 0.f;
    f32x2 acc0 = {0.f, 0.f}, acc1 = {0.f, 0.f}, acc2 = {0.f, 0.f}, acc3 = {0.f, 0.f};

#define PROCESS(cur)                                                     \
    {                                                                    \
        f32x2 v0 = mkf2(cur.x), v1 = mkf2(cur.y),                        \
              v2 = mkf2(cur.z), v3 = mkf2(cur.w);                        \
        f32x2 p = a60 * v0;                                              \
        p = a61 * v1 + p;                                                \
        p = a62 * v2 + p;                                                \
        p = a63 * v3 + p;                                                \
        p = a40 * absf2(v0 + rv0) + p;                                   \
        p = a41 * absf2(v1 + rv1) + p;                                   \
        p = a42 * absf2(v2 + rv2) + p;                                   \
        p = a43 * absf2(v3 + rv3) + p;                                   \
        float pdot = p.x + p.y;                                          \
        pdot += xor1_dpp(pdot);                                          \
        pdot += xor2_dpp(pdot);                                          \
        pdot += xor4_swz(pdot);                                          \
        float wgt = __expf(pdot);                                        \
        den += wgt;                                                      \
        f32x2 wv = {wgt, wgt};                                           \
        acc0 = wv * v0 + acc0;                                           \
        acc1 = wv * v1 + acc1;                                           \
        acc2 = wv * v2 + acc2;                                           \
        acc3 = wv * v3 + acc3;                                           \
    }

    for (int base = beg; base < end; base += 64) {
        int idx = base + lane;
        int srcs = csr_src[idx < end ? idx : end - 1];   // coalesced batch load
        int cnt = min(64, end - base);
        int j = 0;
        for (; j + 8 <= cnt; j += 8) {
            uint4 q[8];
#pragma unroll
            for (int u = 0; u < 8; ++u) {
                int ss = __shfl(srcs, j + u);
                q[u] = *(const uint4*)(xlr + (size_t)ss * 1024 + off);
            }
#pragma unroll
            for (int u = 0; u < 8; ++u) PROCESS(q[u]);
        }
        for (; j < cnt; ++j) {
            int ss = __shfl(srcs, j);
            uint4 qq = *(const uint4*)(xlr + (size_t)ss * 1024 + off);
            PROCESS(qq);
        }
    }
#undef PROCESS

    // normalize per head (0.125 head-mean folded in), reduce over heads (xor 8,16,32)
    float invden = 0.125f / den;
    f32x2 iv = {invden, invden};
    acc0 *= iv; acc1 *= iv; acc2 *= iv; acc3 *= iv;
    float acc[8] = {acc0.x, acc0.y, acc1.x, acc1.y, acc2.x, acc2.y, acc3.x, acc3.y};
#pragma unroll
    for (int k2 = 0; k2 < 8; ++k2) {
        acc[k2] += xor8_dpp(acc[k2]);
        acc[k2] += xor16_swz(acc[k2]);
        acc[k2] += __shfl_xor(acc[k2], 32);
    }

    // bias + residual; LN stats across channels
    int cbase = i * 8;
    const float4* px = (const float4*)(x_in + n * 64 + cbase);
    float4 x0 = px[0], x1 = px[1];
    float xi[8] = {x0.x, x0.y, x0.z, x0.w, x1.x, x1.y, x1.z, x1.w};
    float v[8];
    float sum = 0.f, sq = 0.f;
#pragma unroll
    for (int k2 = 0; k2 < 8; ++k2) {
        float val = acc[k2] + bias[cbase + k2] + xi[k2];
        v[k2] = val; sum += val; sq += val * val;
    }
    sum += xor1_dpp(sum); sq += xor1_dpp(sq);
    sum += xor2_dpp(sum); sq += xor2_dpp(sq);
    sum += xor4_swz(sum); sq += xor4_swz(sq);
    float mu   = sum * (1.0f / 64.0f);
    float var  = sq * (1.0f / 64.0f) - mu * mu;
    float rstd = rsqrtf(var + LN_EPS);

    if (h == 0) {
        float o[8];
#pragma unroll
        for (int k2 = 0; k2 < 8; ++k2) {
            float y = (v[k2] - mu) * rstd * gamma[cbase + k2] + beta[cbase + k2];
            o[k2] = fmaxf(y, 0.f);
        }
        float4* po = (float4*)(x_out + n * 64 + cbase);
        po[0] = make_float4(o[0], o[1], o[2], o[3]);
        po[1] = make_float4(o[4], o[5], o[6], o[7]);
        *(uint4*)(xb_out + (size_t)n * 64 + cbase) =
            make_uint4(pack_bf2(o[0], o[1]), pack_bf2(o[2], o[3]),
                       pack_bf2(o[4], o[5]), pack_bf2(o[6], o[7]));
    }
}

// ---------------- host ----------------

extern "C" void kernel_launch(void* const* d_in, const int* in_sizes, int n_in,
                              void* d_out, int out_size, void* d_ws, size_t ws_size,
                              hipStream_t stream) {
    const float* x     = (const float*)d_in[0];
    const float* Wl    = (const float*)d_in[1];
    const float* Wr    = (const float*)d_in[2];
    const float* att   = (const float*)d_in[3];
    const float* b     = (const float*)d_in[4];
    const float* gamma = (const float*)d_in[5];
    const float* beta  = (const float*)d_in[6];
    const int*   ei    = (const int*)d_in[7];
    float* out = (float*)d_out;

    ushort_t* xlr = (ushort_t*)d_ws;                       // N*1024 bf16
    ushort_t* xb  = xlr + (size_t)N_NODES * 1024;          // PAD_N*64 bf16
    ushort_t* Wt  = xb + (size_t)PAD_N * 64;               // 3*1024*64 bf16
    int* counts     = (int*)(Wt + 3 * 1024 * 64);          // PAD_N
    int* offsets    = counts + PAD_N;                      // PAD_N (N+1 used)
    int* cursor     = offsets + PAD_N;                     // PAD_N
    int* bsum       = cursor + PAD_N;                      // 256
    int* node_order = bsum + 256;                          // PAD_N
    int* bhist      = node_order + PAD_N;                  // 256*64
    int* pbase      = bhist + SCAN_BLOCKS * 64;            // 256*64
    int* csr_src    = pbase + SCAN_BLOCKS * 64;            // EP

    hipMemsetAsync(counts, 0, N_NODES * sizeof(int), stream);

    // setup: edge histogram + x/W bf16 conversion in one launch
    int setup_threads = EP + N_NODES * 64 + 3 * 1024 * 64;
    setup_all<<<(setup_threads + 255) / 256, 256, 0, stream>>>(ei, counts, x, Wl, Wr, xb, Wt);

    csr_scan1<<<SCAN_BLOCKS, 256, 0, stream>>>(counts, bsum, bhist);
    csr_scan2<<<1, 256, 0, stream>>>(bsum, bhist, pbase);
    csr_scan3<<<SCAN_BLOCKS, 256, 0, stream>>>(counts, bsum, offsets, cursor, pbase, node_order);

    int eb = (EP + 255) / 256;
    const float* xin = x;
    for (int l = 0; l < 3; ++l) {
        int grid = (l == 0) ? GEMM_BLOCKS + eb : GEMM_BLOCKS;   // layer 0 also scatters CSR
        gemm_mfma <<<grid, 256, 0, stream>>>(xb, Wt + (size_t)l * 1024 * 64, xlr, ei, cursor, csr_src);
        node_fused<<<N_NODES / 4, 256, 0, stream>>>(xin, xlr, att + l * (H * D), offsets, csr_src,
                                                    node_order, b + l * D, gamma + l * D, beta + l * D,
                                                    out, xb);
        xin = out;
    }
}

// Round 12
// 465.668 us; speedup vs baseline: 1.1757x; 1.0016x over previous
//
#include <hip/hip_runtime.h>

#define N_NODES 50000
#define N_EDGES 400000
#define EP (N_EDGES + N_NODES)   // 450000 edges incl. self-loops
#define D 64
#define H 8
#define NEG_SLOPE 0.2f
#define LN_EPS 1e-5f
#define CHUNK 196
#define SCAN_BLOCKS 256
#define PAD_N 50048
#define GEMM_BLOCKS (782 * 8)    // PAD_N/64 x 8 col-quarters
#define LOG2E 1.4426950408889634f

typedef unsigned short ushort_t;
typedef unsigned int uint_t;
typedef __attribute__((ext_vector_type(8))) short short8;
typedef __attribute__((ext_vector_type(4))) float f32x4;
typedef __attribute__((ext_vector_type(2))) float f32x2;

#if defined(__has_builtin)
#if __has_builtin(__builtin_amdgcn_cvt_pk_bf16_f32)
#define HAVE_CVT_PK_BF16 1
#endif
#endif

__device__ __forceinline__ ushort_t f2bf(float f) {
    uint_t u = __float_as_uint(f);
    u += 0x7fffu + ((u >> 16) & 1u);          // round-to-nearest-even
    return (ushort_t)(u >> 16);
}
__device__ __forceinline__ uint_t pack_bf2(float a, float b) {
#ifdef HAVE_CVT_PK_BF16
    typedef __attribute__((ext_vector_type(2))) __bf16 bf16x2_t;
    bf16x2_t v = __builtin_amdgcn_cvt_pk_bf16_f32(a, b);
    uint_t r;
    __builtin_memcpy(&r, &v, 4);
    return r;
#else
    return (uint_t)f2bf(a) | ((uint_t)f2bf(b) << 16);
#endif
}
__device__ __forceinline__ f32x2 mkf2(uint_t u) {
    f32x2 r;
    r.x = __uint_as_float(u << 16);
    r.y = __uint_as_float(u & 0xffff0000u);
    return r;
}

// ---- forced packed-fp32 VALU ops (compiler won't form v_pk_*_f32 from generic IR) ----
__device__ __forceinline__ f32x2 pk_add(f32x2 a, f32x2 b) {
    f32x2 d;
    asm("v_pk_add_f32 %0, %1, %2" : "=v"(d) : "v"(a), "v"(b));
    return d;
}
__device__ __forceinline__ f32x2 pk_mul(f32x2 a, f32x2 b) {
    f32x2 d;
    asm("v_pk_mul_f32 %0, %1, %2" : "=v"(d) : "v"(a), "v"(b));
    return d;
}
__device__ __forceinline__ f32x2 pk_fma(f32x2 a, f32x2 b, f32x2 c) {
    f32x2 d;
    asm("v_pk_fma_f32 %0, %1, %2, %3" : "=v"(d) : "v"(a), "v"(b), "v"(c));
    return d;
}
__device__ __forceinline__ f32x2 pk_abs(f32x2 a) {     // no v_pk_max_f32 on gfx950: 2x v_and_b32
    f32x2 r;
    r.x = __uint_as_float(__float_as_uint(a.x) & 0x7fffffffu);
    r.y = __uint_as_float(__float_as_uint(a.y) & 0x7fffffffu);
    return r;
}

// cross-lane reduce helpers: DPP for xor1/xor2/xor8 (pure VALU), ds_swizzle for xor4/xor16
__device__ __forceinline__ float xor1_dpp(float x) {   // quad_perm [1,0,3,2]
    int i = __float_as_int(x);
    return __int_as_float(__builtin_amdgcn_update_dpp(i, i, 0xB1, 0xF, 0xF, 1));
}
__device__ __forceinline__ float xor2_dpp(float x) {   // quad_perm [2,3,0,1]
    int i = __float_as_int(x);
    return __int_as_float(__builtin_amdgcn_update_dpp(i, i, 0x4E, 0xF, 0xF, 1));
}
__device__ __forceinline__ float xor8_dpp(float x) {   // ROW_ROR:8 == lane^8 within 16-row
    int i = __float_as_int(x);
    return __int_as_float(__builtin_amdgcn_update_dpp(i, i, 0x128, 0xF, 0xF, 1));
}
__device__ __forceinline__ float xor4_swz(float x) {   // ds_swizzle xor 4
    return __int_as_float(__builtin_amdgcn_ds_swizzle(__float_as_int(x), 0x101F));
}
__device__ __forceinline__ float xor16_swz(float x) {  // ds_swizzle xor 16
    return __int_as_float(__builtin_amdgcn_ds_swizzle(__float_as_int(x), 0x401F));
}

// decode edge id -> (src, dst); ids >= N_EDGES are self-loops
__device__ __forceinline__ void edge_sd(const int* __restrict__ ei, int eid, int& s, int& d) {
    if (eid < N_EDGES) { s = ei[eid]; d = ei[N_EDGES + eid]; }
    else               { s = d = eid - N_EDGES; }
}

// ---------------- setup: edge histogram + bf16 conversions (one kernel) ----------------

__global__ __launch_bounds__(256) void setup_all(const int* __restrict__ ei, int* __restrict__ counts,
                                                 const float* __restrict__ x,
                                                 const float* __restrict__ Wl, const float* __restrict__ Wr,
                                                 ushort_t* __restrict__ xb, ushort_t* __restrict__ Wt) {
    int t = blockIdx.x * 256 + threadIdx.x;
    if (t < EP) {
        int s, d; edge_sd(ei, t, s, d);
        atomicAdd(&counts[d], 1);
        return;
    }
    t -= EP;
    if (t < N_NODES * 64) { xb[t] = f2bf(x[t]); return; }
    t -= N_NODES * 64;
    if (t >= 3 * 1024 * 64) return;
    int l = t >> 16, rem = t & 65535, col = rem >> 6, k = rem & 63;
    float v = (col < 512) ? Wl[((size_t)l * 64 + k) * 512 + col]
                          : Wr[((size_t)l * 64 + k) * 512 + (col - 512)];
    Wt[t] = f2bf(v);
}

// ---------------- CSR scans + degree sort ----------------

__global__ __launch_bounds__(256) void csr_scan1(const int* __restrict__ counts, int* __restrict__ bsum,
                                                 int* __restrict__ bhist) {
    __shared__ int sd[256];
    __shared__ int hist[64];
    int t = threadIdx.x, b = blockIdx.x;
    if (t < 64) hist[t] = 0;
    int idx = b * CHUNK + t;
    int v = (t < CHUNK && idx < N_NODES) ? counts[idx] : 0;
    sd[t] = v;
    __syncthreads();
    if (t < CHUNK && idx < N_NODES) atomicAdd(&hist[63 - min(v, 63)], 1);
    for (int d = 128; d > 0; d >>= 1) {
        __syncthreads();
        if (t < d) sd[t] += sd[t + d];
    }
    __syncthreads();
    if (t == 0) bsum[b] = sd[0];
    if (t < 64) bhist[b * 64 + t] = hist[t];
}

__global__ __launch_bounds__(256) void csr_scan2(int* __restrict__ bsum,
                                                 const int* __restrict__ bhist, int* __restrict__ pbase) {
    __shared__ int sd[256];
    __shared__ int sg[64 * 4];
    __shared__ int base[64];
    int t = threadIdx.x;
    sd[t] = bsum[t];
    __syncthreads();
    for (int d = 1; d < 256; d <<= 1) {
        int v = (t >= d) ? sd[t - d] : 0;
        __syncthreads();
        if (t >= d) sd[t] += v;
        __syncthreads();
    }
    bsum[t] = (t > 0) ? sd[t - 1] : 0;

    int k = t & 63, g = t >> 6;
    int s = 0;
    for (int j = 0; j < 64; ++j) s += bhist[(g * 64 + j) * 64 + k];
    sg[k * 4 + g] = s;
    __syncthreads();
    if (t == 0) {
        int run = 0;
        for (int kk = 0; kk < 64; ++kk) {
            base[kk] = run;
            run += sg[kk * 4 + 0] + sg[kk * 4 + 1] + sg[kk * 4 + 2] + sg[kk * 4 + 3];
        }
    }
    __syncthreads();
    int run = base[k];
    for (int gg = 0; gg < g; ++gg) run += sg[k * 4 + gg];
    for (int j = 0; j < 64; ++j) {
        int b = g * 64 + j;
        pbase[b * 64 + k] = run;
        run += bhist[b * 64 + k];
    }
}

__global__ __launch_bounds__(256) void csr_scan3(const int* __restrict__ counts, const int* __restrict__ bsum,
                                                 int* __restrict__ offsets, int* __restrict__ cursor,
                                                 const int* __restrict__ pbase, int* __restrict__ node_order) {
    __shared__ int sd[256];
    __shared__ int cur[64];
    int t = threadIdx.x, b = blockIdx.x;
    if (t < 64) cur[t] = pbase[b * 64 + t];
    int idx = b * CHUNK + t;
    int v = (t < CHUNK && idx < N_NODES) ? counts[idx] : 0;
    sd[t] = v;
    __syncthreads();
    for (int d = 1; d < 256; d <<= 1) {
        int u = (t >= d) ? sd[t - d] : 0;
        __syncthreads();
        if (t >= d) sd[t] += u;
        __syncthreads();
    }
    if (t < CHUNK && idx < N_NODES) {
        int ex = bsum[b] + sd[t] - v;
        offsets[idx] = ex;
        cursor[idx]  = ex;
        int bin = 63 - min(v, 63);
        int p = atomicAdd(&cur[bin], 1);
        node_order[p] = idx;
    }
    if (b == 0 && t == 0) offsets[N_NODES] = EP;
}

// ---------------- MFMA GEMM (LDS-staged W), with CSR-scatter blocks appended on layer 0 ----------------
__global__ __launch_bounds__(256) void gemm_mfma(const ushort_t* __restrict__ xb,
                                                 const ushort_t* __restrict__ Wt,
                                                 ushort_t* __restrict__ xlr,
                                                 const int* __restrict__ ei, int* __restrict__ cursor,
                                                 int* __restrict__ csr_src) {
    __shared__ ushort_t sW[128 * 72];    // 128 cols x 64 k, rows padded to 72 shorts
    int b = blockIdx.x;
    if (b >= GEMM_BLOCKS) {              // scatter part (layer-0 launch only)
        int t = (b - GEMM_BLOCKS) * 256 + threadIdx.x;
        if (t >= EP) return;
        int s, d; edge_sd(ei, t, s, d);
        int pos = atomicAdd(&cursor[d], 1);
        csr_src[pos] = s;
        return;
    }
    int colq = b / 782;
    int bx = b - colq * 782;
    int t = threadIdx.x;
    const ushort_t* Wg = Wt + (size_t)colq * 128 * 64;
    {
        int col = t >> 1, half = t & 1;
        const uint4* g = (const uint4*)(Wg + col * 64 + half * 32);
        uint4* l = (uint4*)(sW + col * 72 + half * 32);
        l[0] = g[0]; l[1] = g[1]; l[2] = g[2]; l[3] = g[3];
    }
    __syncthreads();
    int lane = t & 63, w = t >> 6;
    int ln = lane & 15, q = lane >> 4;
    int node = bx * 64 + w * 16 + ln;
    int nclamp = node < N_NODES ? node : N_NODES - 1;
    const short8 b0 = *(const short8*)(xb + (size_t)nclamp * 64 + q * 8);
    const short8 b1 = *(const short8*)(xb + (size_t)nclamp * 64 + 32 + q * 8);
#pragma unroll
    for (int ct = 0; ct < 8; ++ct) {
        const short8 a0 = *(const short8*)(sW + (ct * 16 + ln) * 72 + q * 8);
        const short8 a1 = *(const short8*)(sW + (ct * 16 + ln) * 72 + 32 + q * 8);
        f32x4 acc = {0.f, 0.f, 0.f, 0.f};
        acc = __builtin_amdgcn_mfma_f32_16x16x32_bf16(a0, b0, acc, 0, 0, 0);
        acc = __builtin_amdgcn_mfma_f32_16x16x32_bf16(a1, b1, acc, 0, 0, 0);
        if (node < N_NODES) {
            uint_t lo = pack_bf2(acc[0], acc[1]);
            uint_t hi = pack_bf2(acc[2], acc[3]);
            *(uint2*)(xlr + (size_t)node * 1024 + colq * 128 + ct * 16 + q * 4) = make_uint2(lo, hi);
        }
    }
}

// ---------------- fused node kernel (forced v_pk_* math, DPP reduces) ----------------
// leaky(t)=0.6t+0.4|t| -> a.leaky(v+r) = (0.6a).v + (0.4a).|v+r| + const(cancels in softmax).
// a60/a40 pre-scaled by log2(e): logit in base-2, exp2 == v_exp_f32 directly; softmax invariant.
__global__ __launch_bounds__(256) void node_fused(const float* __restrict__ x_in,
                                                  const ushort_t* __restrict__ xlr,
                                                  const float* __restrict__ att,
                                                  const int* __restrict__ offsets, const int* __restrict__ csr_src,
                                                  const int* __restrict__ node_order,
                                                  const float* __restrict__ bias, const float* __restrict__ gamma,
                                                  const float* __restrict__ beta, float* __restrict__ x_out,
                                                  ushort_t* __restrict__ xb_out) {
    int n = node_order[blockIdx.x * 4 + (threadIdx.x >> 6)];
    n = __builtin_amdgcn_readfirstlane(n);
    int lane = threadIdx.x & 63;
    int h = lane >> 3, i = lane & 7;
    int beg = __builtin_amdgcn_readfirstlane(offsets[n]);
    int end = __builtin_amdgcn_readfirstlane(offsets[n + 1]);
    int off = h * 64 + i * 8;

    // loop-invariants
    uint4 ru = *(const uint4*)(xlr + (size_t)n * 1024 + 512 + off);
    f32x2 rv0 = mkf2(ru.x), rv1 = mkf2(ru.y), rv2 = mkf2(ru.z), rv3 = mkf2(ru.w);
    const float4* pa = (const float4*)(att + h * 64 + i * 8);
    float4 aa = pa[0], ab = pa[1];
    f32x2 a0 = {aa.x, aa.y}, a1 = {aa.z, aa.w}, a2 = {ab.x, ab.y}, a3 = {ab.z, ab.w};
    f32x2 a60 = (0.6f * LOG2E) * a0, a61 = (0.6f * LOG2E) * a1,
          a62 = (0.6f * LOG2E) * a2, a63 = (0.6f * LOG2E) * a3;
    f32x2 a40 = (0.4f * LOG2E) * a0, a41 = (0.4f * LOG2E) * a1,
          a42 = (0.4f * LOG2E) * a2, a43 = (0.4f * LOG2E) * a3;

    float den = 0.f;
    f32x2 acc0 = {0.f, 0.f}, acc1 = {0.f, 0.f}, acc2 = {0.f, 0.f}, acc3 = {0.f, 0.f};

#define PROCESS(cur)                                                     \
    {                                                                    \
        f32x2 v0 = mkf2(cur.x), v1 = mkf2(cur.y),                        \
              v2 = mkf2(cur.z), v3 = mkf2(cur.w);                        \
        f32x2 p = pk_mul(a60, v0);                                       \
        p = pk_fma(a61, v1, p);                                          \
        p = pk_fma(a62, v2, p);                                          \
        p = pk_fma(a63, v3, p);                                          \
        p = pk_fma(a40, pk_abs(pk_add(v0, rv0)), p);                     \
        p = pk_fma(a41, pk_abs(pk_add(v1, rv1)), p);                     \
        p = pk_fma(a42, pk_abs(pk_add(v2, rv2)), p);                     \
        p = pk_fma(a43, pk_abs(pk_add(v3, rv3)), p);                     \
        float pdot = p.x + p.y;                                          \
        pdot += xor1_dpp(pdot);                                          \
        pdot += xor2_dpp(pdot);                                          \
        pdot += xor4_swz(pdot);                                          \
        float wgt = __builtin_exp2f(pdot);                               \
        den += wgt;                                                      \
        f32x2 wv = {wgt, wgt};                                           \
        acc0 = pk_fma(wv, v0, acc0);                                     \
        acc1 = pk_fma(wv, v1, acc1);                                     \
        acc2 = pk_fma(wv, v2, acc2);                                     \
        acc3 = pk_fma(wv, v3, acc3);                                     \
    }

    for (int base = beg; base < end; base += 64) {
        int idx = base + lane;
        int srcs = csr_src[idx < end ? idx : end - 1];   // coalesced batch load
        int cnt = min(64, end - base);
        int j = 0;
        for (; j + 8 <= cnt; j += 8) {
            uint4 q[8];
#pragma unroll
            for (int u = 0; u < 8; ++u) {
                int ss = __shfl(srcs, j + u);
                q[u] = *(const uint4*)(xlr + (size_t)ss * 1024 + off);
            }
#pragma unroll
            for (int u = 0; u < 8; ++u) PROCESS(q[u]);
        }
        for (; j < cnt; ++j) {
            int ss = __shfl(srcs, j);
            uint4 qq = *(const uint4*)(xlr + (size_t)ss * 1024 + off);
            PROCESS(qq);
        }
    }
#undef PROCESS

    // normalize per head (0.125 head-mean folded in), reduce over heads (xor 8,16,32)
    float invden = 0.125f / den;
    f32x2 iv = {invden, invden};
    acc0 = pk_mul(acc0, iv); acc1 = pk_mul(acc1, iv);
    acc2 = pk_mul(acc2, iv); acc3 = pk_mul(acc3, iv);
    float acc[8] = {acc0.x, acc0.y, acc1.x, acc1.y, acc2.x, acc2.y, acc3.x, acc3.y};
#pragma unroll
    for (int k2 = 0; k2 < 8; ++k2) {
        acc[k2] += xor8_dpp(acc[k2]);
        acc[k2] += xor16_swz(acc[k2]);
        acc[k2] += __shfl_xor(acc[k2], 32);
    }

    // bias + residual; LN stats across channels
    int cbase = i * 8;
    const float4* px = (const float4*)(x_in + n * 64 + cbase);
    float4 x0 = px[0], x1 = px[1];
    float xi[8] = {x0.x, x0.y, x0.z, x0.w, x1.x, x1.y, x1.z, x1.w};
    float v[8];
    float sum = 0.f, sq = 0.f;
#pragma unroll
    for (int k2 = 0; k2 < 8; ++k2) {
        float val = acc[k2] + bias[cbase + k2] + xi[k2];
        v[k2] = val; sum += val; sq += val * val;
    }
    sum += xor1_dpp(sum); sq += xor1_dpp(sq);
    sum += xor2_dpp(sum); sq += xor2_dpp(sq);
    sum += xor4_swz(sum); sq += xor4_swz(sq);
    float mu   = sum * (1.0f / 64.0f);
    float var  = sq * (1.0f / 64.0f) - mu * mu;
    float rstd = rsqrtf(var + LN_EPS);

    if (h == 0) {
        float o[8];
#pragma unroll
        for (int k2 = 0; k2 < 8; ++k2) {
            float y = (v[k2] - mu) * rstd * gamma[cbase + k2] + beta[cbase + k2];
            o[k2] = fmaxf(y, 0.f);
        }
        float4* po = (float4*)(x_out + n * 64 + cbase);
        po[0] = make_float4(o[0], o[1], o[2], o[3]);
        po[1] = make_float4(o[4], o[5], o[6], o[7]);
        *(uint4*)(xb_out + (size_t)n * 64 + cbase) =
            make_uint4(pack_bf2(o[0], o[1]), pack_bf2(o[2], o[3]),
                       pack_bf2(o[4], o[5]), pack_bf2(o[6], o[7]));
    }
}

// ---------------- host ----------------

extern "C" void kernel_launch(void* const* d_in, const int* in_sizes, int n_in,
                              void* d_out, int out_size, void* d_ws, size_t ws_size,
                              hipStream_t stream) {
    const float* x     = (const float*)d_in[0];
    const float* Wl    = (const float*)d_in[1];
    const float* Wr    = (const float*)d_in[2];
    const float* att   = (const float*)d_in[3];
    const float* b     = (const float*)d_in[4];
    const float* gamma = (const float*)d_in[5];
    const float* beta  = (const float*)d_in[6];
    const int*   ei    = (const int*)d_in[7];
    float* out = (float*)d_out;

    ushort_t* xlr = (ushort_t*)d_ws;                       // N*1024 bf16
    ushort_t* xb  = xlr + (size_t)N_NODES * 1024;          // PAD_N*64 bf16
    ushort_t* Wt  = xb + (size_t)PAD_N * 64;               // 3*1024*64 bf16
    int* counts     = (int*)(Wt + 3 * 1024 * 64);          // PAD_N
    int* offsets    = counts + PAD_N;                      // PAD_N (N+1 used)
    int* cursor     = offsets + PAD_N;                     // PAD_N
    int* bsum       = cursor + PAD_N;                      // 256
    int* node_order = bsum + 256;                          // PAD_N
    int* bhist      = node_order + PAD_N;                  // 256*64
    int* pbase      = bhist + SCAN_BLOCKS * 64;            // 256*64
    int* csr_src    = pbase + SCAN_BLOCKS * 64;            // EP

    hipMemsetAsync(counts, 0, N_NODES * sizeof(int), stream);

    // setup: edge histogram + x/W bf16 conversion in one launch
    int setup_threads = EP + N_NODES * 64 + 3 * 1024 * 64;
    setup_all<<<(setup_threads + 255) / 256, 256, 0, stream>>>(ei, counts, x, Wl, Wr, xb, Wt);

    csr_scan1<<<SCAN_BLOCKS, 256, 0, stream>>>(counts, bsum, bhist);
    csr_scan2<<<1, 256, 0, stream>>>(bsum, bhist, pbase);
    csr_scan3<<<SCAN_BLOCKS, 256, 0, stream>>>(counts, bsum, offsets, cursor, pbase, node_order);

    int eb = (EP + 255) / 256;
    const float* xin = x;
    for (int l = 0; l < 3; ++l) {
        int grid = (l == 0) ? GEMM_BLOCKS + eb : GEMM_BLOCKS;   // layer 0 also scatters CSR
        gemm_mfma <<<grid, 256, 0, stream>>>(xb, Wt + (size_t)l * 1024 * 64, xlr, ei, cursor, csr_src);
        node_fused<<<N_NODES / 4, 256, 0, stream>>>(xin, xlr, att + l * (H * D), offsets, csr_src,
                                                    node_order, b + l * D, gamma + l * D, beta + l * D,
                                                    out, xb);
        xin = out;
    }
}